// Round 4
// baseline (130.562 us; speedup 1.0000x reference)
//
#include <hip/hip_runtime.h>
#include <math.h>

// Problem constants (reference: B=1024, C=10, H=30, W=30)
constexpr int BATCH = 1024;
constexpr int NC    = 10;   // n_colors / channels
constexpr int HW    = 900;  // 30*30 pixels per image
constexpr int PAIRS = 225;  // float2 pixel-pairs per half-image

// Main kernel: grid = BATCH*2 blocks of 256 threads; threads 0..224 each own
// 2 consecutive pixels via float2 loads (part*450 + t*2 keeps 8B alignment;
// channel stride 900 floats). All 30 float2 loads are hoisted up-front for
// memory-level parallelism (~60 live floats ≈ 80 VGPR, under the 128 cap of
// launch_bounds(256,4) -- round-1/2 showed the allocator sinks loads when the
// pressure target is 32, serializing everything; round 3 proved hoisting wins).
// Each block plain-stores ONE float4 partial {ce_sum, or_mask, counts, 0} --
// no atomics, no memset.
//
// or_mask bits: 0-9 pred-color-present, 10-19 tgt-color-present,
//              20 any(pred!=tgt), 21 any(tgt!=inp), 22 any(pred!=inp)
// counts: changed + (tchanged<<16)
__global__ __launch_bounds__(256, 4) void loss_main(
    const float* __restrict__ pred, const float* __restrict__ target,
    const float* __restrict__ inp, float4* __restrict__ ws) {
  const int img  = blockIdx.x >> 1;
  const int part = blockIdx.x & 1;
  const int t    = threadIdx.x;

  float ce_sum = 0.f;
  unsigned combo = 0;
  int counts = 0;

  if (t < PAIRS) {
    const size_t base = (size_t)img * NC * HW + part * (HW / 2) + t * 2;

    // ---- 30 independent float2 loads, all issued before any use ----
    float2 p2[NC], t2[NC], g2[NC];
#pragma unroll
    for (int c = 0; c < NC; ++c) p2[c] = *(const float2*)(pred + base + c * HW);
#pragma unroll
    for (int c = 0; c < NC; ++c) t2[c] = *(const float2*)(target + base + c * HW);
#pragma unroll
    for (int c = 0; c < NC; ++c) g2[c] = *(const float2*)(inp + base + c * HW);

#pragma unroll
    for (int j = 0; j < 2; ++j) {
      float p[NC], tv[NC], gv[NC];
#pragma unroll
      for (int c = 0; c < NC; ++c) {
        p[c]  = j ? p2[c].y : p2[c].x;
        tv[c] = j ? t2[c].y : t2[c].x;
        gv[c] = j ? g2[c].y : g2[c].x;
      }

      // pred argmax (strict > = first-index tie-break)
      float pmax = p[0]; int pidx = 0;
#pragma unroll
      for (int c = 1; c < NC; ++c)
        if (p[c] > pmax) { pmax = p[c]; pidx = c; }

      // stable log-sum-exp: 10 independent exps
      float s = 0.f;
#pragma unroll
      for (int c = 0; c < NC; ++c) s += __expf(p[c] - pmax);
      const float lse = pmax + __logf(s);

      // target / input argmax
      float tmax = tv[0]; int tidx = 0;
#pragma unroll
      for (int c = 1; c < NC; ++c)
        if (tv[c] > tmax) { tmax = tv[c]; tidx = c; }
      float gmax = gv[0]; int gidx = 0;
#pragma unroll
      for (int c = 1; c < NC; ++c)
        if (gv[c] > gmax) { gmax = gv[c]; gidx = c; }

      // pred value at target index (cndmask chain)
      float ptv = p[0];
#pragma unroll
      for (int c = 1; c < NC; ++c)
        if (tidx == c) ptv = p[c];

      const float ce = lse - ptv;
      const float w  = (pidx != tidx) ? 5.0f : 1.0f;  // 1 + 4*incorrect
      ce_sum += ce * w;
      combo  |= (1u << pidx) | (1u << (10 + tidx));
      if (pidx != tidx) combo |= 1u << 20;
      if (tidx != gidx) combo |= 1u << 21;
      if (pidx != gidx) combo |= 1u << 22;
      counts += ((pidx != gidx) ? 1 : 0) + ((tidx != gidx) ? (1 << 16) : 0);
    }
  }

  // ---- wave(64) reduction of 3 quantities ----
#pragma unroll
  for (int off = 32; off >= 1; off >>= 1) {
    ce_sum += __shfl_down(ce_sum, off);
    combo  |= __shfl_down(combo, off);
    counts += __shfl_down(counts, off);
  }

  __shared__ float s_ce[4];
  __shared__ unsigned s_or[4];
  __shared__ int s_cnt[4];
  const int wave = t >> 6;
  if ((t & 63) == 0) { s_ce[wave] = ce_sum; s_or[wave] = combo; s_cnt[wave] = counts; }
  __syncthreads();
  if (t == 0) {
    float4 slot;
    slot.x = s_ce[0] + s_ce[1] + s_ce[2] + s_ce[3];
    slot.y = __uint_as_float(s_or[0] | s_or[1] | s_or[2] | s_or[3]);
    slot.z = __int_as_float(s_cnt[0] + s_cnt[1] + s_cnt[2] + s_cnt[3]);
    slot.w = 0.f;
    ws[blockIdx.x] = slot;
  }
}

// Finalize: single block, 1024 threads, thread b = image b. Combines the 2
// block-partials of its image (32 KB total read), computes per-image terms,
// block-reduces the 5 global sums, thread 0 writes the 6 outputs.
__global__ __launch_bounds__(1024) void loss_final(
    const float4* __restrict__ ws, float* __restrict__ out) {
  const int b = threadIdx.x;

  float ce = 0.f; unsigned orv = 0; int cnt = 0;
#pragma unroll
  for (int k = 0; k < 2; ++k) {
    const float4 v = ws[b * 2 + k];
    ce  += v.x;
    orv |= __float_as_uint(v.y);
    cnt += __float_as_int(v.z);
  }
  const int changed  = cnt & 0xFFFF;
  const int tchanged = cnt >> 16;
  const float exact   = (orv & (1u << 20)) ? 0.f : 1.f;     // all(pred==tgt)
  const float any_ti  = (orv & (1u << 21)) ? 1.f : 0.f;     // any(tgt!=inp)
  const float all_pi  = (orv & (1u << 22)) ? 0.f : 1.f;     // all(pred==inp)
  const unsigned pm = orv & 0x3FFu, tm = (orv >> 10) & 0x3FFu;
  const float d = (float)(changed - tchanged) * (1.0f / (float)HW);

  float r_ce = ce;                       // sum of weighted CE
  float r_ex = exact;                    // exact-match count
  float r_cp = any_ti * all_pi;          // copy-penalty count
  float r_td = d * d;                    // transform-diff sum
  float r_mi = (float)__popc(tm & ~pm);  // missing colors

#pragma unroll
  for (int off = 32; off >= 1; off >>= 1) {
    r_ce += __shfl_down(r_ce, off);
    r_ex += __shfl_down(r_ex, off);
    r_cp += __shfl_down(r_cp, off);
    r_td += __shfl_down(r_td, off);
    r_mi += __shfl_down(r_mi, off);
  }

  __shared__ float red[16][5];
  const int wave = b >> 6;
  if ((b & 63) == 0) {
    red[wave][0] = r_ce; red[wave][1] = r_ex; red[wave][2] = r_cp;
    red[wave][3] = r_td; red[wave][4] = r_mi;
  }
  __syncthreads();
  if (b == 0) {
    float a0 = 0, a1 = 0, a2 = 0, a3 = 0, a4 = 0;
#pragma unroll
    for (int w = 0; w < 16; ++w) {
      a0 += red[w][0]; a1 += red[w][1]; a2 += red[w][2];
      a3 += red[w][3]; a4 += red[w][4];
    }
    const float ce_loss    = a0 * (1.0f / ((float)BATCH * (float)HW));
    const float exact_sum  = a1;
    const float exact_frac = exact_sum * (1.0f / (float)BATCH);
    const float copy_pen   = 5.0f * a2 * (1.0f / (float)BATCH);
    const float tdiff      = a3 * (1.0f / (float)BATCH);
    const float color_pen  = 0.1f * a4;
    float total = ce_loss - exact_frac + copy_pen + tdiff + color_pen;
    if (isnan(total)) total = 2.0f;
    else if (total > 100.0f) total = 10.0f;
    out[0] = total;
    out[1] = ce_loss;
    out[2] = copy_pen;
    out[3] = exact_frac;
    out[4] = exact_sum;
    out[5] = tdiff;
  }
}

extern "C" void kernel_launch(void* const* d_in, const int* in_sizes, int n_in,
                              void* d_out, int out_size, void* d_ws, size_t ws_size,
                              hipStream_t stream) {
  const float* pred   = (const float*)d_in[0];
  const float* target = (const float*)d_in[1];
  const float* inp    = (const float*)d_in[2];
  float4* ws = (float4*)d_ws;  // 2048 slots * 16 B = 32 KB; fully written
                               // every launch before being read -> no memset.
  loss_main<<<dim3(BATCH * 2), dim3(256), 0, stream>>>(pred, target, inp, ws);
  loss_final<<<dim3(1), dim3(1024), 0, stream>>>(ws, (float*)d_out);
}